// Round 13
// baseline (119.060 us; speedup 1.0000x reference)
//
#include <hip/hip_runtime.h>

typedef short short8 __attribute__((ext_vector_type(8)));
typedef short short4v __attribute__((ext_vector_type(4)));
typedef float floatx4 __attribute__((ext_vector_type(4)));

#define BB 4
#define CC 124
#define CP 128
#define NN 4096
#define NGRP 256               // 16-position groups per batch (kfrag)
#define NG32 128               // 32-key groups per batch (vfrag)
#define NSPLIT 4
#define KSPLIT (NN / NSPLIT)   // 1024 keys per split
#define TN 64                  // keys per chunk
#define NCHUNK (KSPLIT / TN)   // 16
// retained-set softmax cutoff (log2 units): contributions < 2^-24 dropped.
// off-diag args here are ~-179 +- 16, diag = 0 -> skip fires on ~98% of
// (wave,window) pairs; dropped mass <= 4096*2^-24*|V|*gamma/L ~ 1e-4.
// [R12 measured: attn 40.6 -> 31.6us, absmax unchanged 0.03125]
#define SKIP_THR -24.0f

static __device__ __forceinline__ unsigned short f2bf_fast(float f) {
    return (unsigned short)((__float_as_uint(f) + 0x8000u) >> 16);
}
static __device__ __forceinline__ float bf2f(unsigned short u) {
    return __uint_as_float(((unsigned int)u) << 16);
}
// pack bf16(a) low16 | bf16(b) high16: 2 adds + 1 v_perm
static __device__ __forceinline__ unsigned int pkbf(float a, float b) {
    unsigned int ua = __float_as_uint(a) + 0x8000u;
    unsigned int ub = __float_as_uint(b) + 0x8000u;
    return __builtin_amdgcn_perm(ub, ua, 0x07060302u);
}
union PK2 { short4v s; unsigned int u[2]; };
union PK8 { short8 s; unsigned int u[4]; };

// Raw hardware exp2: libm exp2f (no fast-math) emits a ~7-inst guarded
// sequence for args < -126; our stabilized scores hit that range constantly
// and the flush-to-zero result is numerically irrelevant (L >= ~1).
#if defined(__has_builtin) && __has_builtin(__builtin_amdgcn_exp2f)
static __device__ __forceinline__ float exp2_raw(float x) {
    return __builtin_amdgcn_exp2f(x);
}
#else
static __device__ __forceinline__ float exp2_raw(float x) {
    float r;
    // s_nop 0 = 1 wait state for the TRANS->VALU consumer hazard
    asm("v_exp_f32 %0, %1\n\ts_nop 0" : "=v"(r) : "v"(x));
    return r;
}
#endif

// async global->LDS: 16B/lane, lds dest = wave-uniform base + lane*16
static __device__ __forceinline__ void gl16(const unsigned short* g, unsigned short* l) {
    __builtin_amdgcn_global_load_lds(
        (const __attribute__((address_space(1))) unsigned int*)g,
        (__attribute__((address_space(3))) unsigned int*)l, 16, 0, 0);
}

// ---------------------------------------------------------------------------
// One-time Wb transpose -> wbt[c][o] bf16 (o padded to 128 with zeros).
// Coalesced Wb reads, LDS transpose (stride-125 conflict-free), coalesced writes.
// ---------------------------------------------------------------------------
__global__ __launch_bounds__(256) void wtrans_kernel(const float* __restrict__ Wb,
                                                     unsigned short* __restrict__ wbt) {
    __shared__ float ws[32][125];
    const int blk = blockIdx.x;      // o-range blk*32 .. +31
    const int tid = threadIdx.x;
    for (int i = tid; i < 32 * CC; i += 256) {
        int ol = i / CC, c = i - ol * CC;
        int o = blk * 32 + ol;
        ws[ol][c] = (o < CC) ? Wb[o * CC + c] : 0.f;
    }
    __syncthreads();
    for (int i = tid; i < CC * 32; i += 256) {
        int c = i >> 5, ol = i & 31;
        wbt[c * CP + blk * 32 + ol] = f2bf_fast(ws[ol][c]);
    }
}

// ---------------------------------------------------------------------------
// Projection Bf = Wb x -> bf16 MFMA fragments, with the PV-enabling KEY
// PERMUTATION baked in:  position p within each 32-block = 16*((n>>2)&1) +
// 4*((n>>3)&3) + (n&3).  kfrag is position-indexed (QK A and Q B operands);
// vfrag is K=32 B-frag layout in ACTUAL key order:
//   vfrag[b][g32][s8][lane]*8 : 16B = V[keys 8*quad..+8][c = s8*16+col]
// V channel 124 = 1.0 -> PV computes l in O[m][124] for free.
// m2[b][n] = log2(e)*||Bf[:,n]||^2 (fixed stabilizer; diagonal dominates).
// Wb read from global wbt (L1-resident 32KB broadcast) -- no W in LDS.
// ---------------------------------------------------------------------------
__global__ __launch_bounds__(256, 4) void bf_proj_kernel(const float* __restrict__ x,
                                                         const unsigned short* __restrict__ wbt,
                                                         unsigned short* __restrict__ kfrag,
                                                         unsigned short* __restrict__ vfrag,
                                                         float* __restrict__ m2) {
    __shared__ __align__(16) float xs[CC][36];
    __shared__ float msh[32][33];
    const int tid = threadIdx.x;
    const int b = blockIdx.y;
    const int n0 = blockIdx.x * 32;
    const float* xb = x + (size_t)b * CC * NN + n0;
    for (int i = tid; i < CC * 8; i += 256) {
        int c = i >> 3, nq = i & 7;
        *(floatx4*)&xs[c][nq * 4] = *(const floatx4*)(xb + (size_t)c * NN + nq * 4);
    }
    __syncthreads();
    const int og = tid >> 3;        // 0..31 -> o0 = og*4
    const int nidx = tid & 7;       // key n_loc = nidx*4 + j
    const int o0 = og * 4;
    float acc[4][4];
#pragma unroll
    for (int k = 0; k < 4; ++k)
#pragma unroll
        for (int j = 0; j < 4; ++j) acc[k][j] = 0.f;
    for (int c = 0; c < CC; ++c) {
        floatx4 xv = *(const floatx4*)&xs[c][nidx * 4];
        short4v wv = *(const short4v*)&wbt[c * CP + o0];
#pragma unroll
        for (int k = 0; k < 4; ++k) {
            float wf = bf2f((unsigned short)wv[k]);
            acc[k][0] += wf * xv[0];
            acc[k][1] += wf * xv[1];
            acc[k][2] += wf * xv[2];
            acc[k][3] += wf * xv[3];
        }
    }
    // stats (per-n partial over this thread's 4 channels)
    float sq[4] = {0.f, 0.f, 0.f, 0.f};
#pragma unroll
    for (int k = 0; k < 4; ++k)
#pragma unroll
        for (int j = 0; j < 4; ++j) sq[j] += acc[k][j] * acc[k][j];
#pragma unroll
    for (int j = 0; j < 4; ++j) msh[og][nidx * 4 + j] = sq[j];
    // ---- kfrag (position-permuted) ----
    const int g16 = (n0 >> 4) + (nidx & 1);      // (n0>>5)*2 + (nidx&1)
    const int tK = o0 >> 5;
    const int qK = (o0 >> 3) & 3;
    const int halfo = o0 & 7;                    // 0 or 4 shorts
#pragma unroll
    for (int j = 0; j < 4; ++j) {
        PK2 kv;
        kv.u[0] = pkbf(acc[0][j], acc[1][j]);
        kv.u[1] = pkbf(acc[2][j], acc[3][j]);
        int row16 = 4 * (nidx >> 1) + j;         // p & 15
        size_t unit = ((size_t)(b * NGRP + g16) * 4 + tK) * 64 + qK * 16 + row16;
        *(short4v*)&kfrag[unit * 8 + halfo] = kv.s;
    }
    // ---- vfrag (K=32 B-frags, natural key order) ----
    const int g32 = n0 >> 5;
    const int quadn = nidx >> 1;                 // (n_loc)>>3
    const int halfn = (nidx & 1) * 4;            // element offset j_in_8 base
#pragma unroll
    for (int k = 0; k < 4; ++k) {
        int c = o0 + k;
        PK2 vv;
        if (c == 124) {
            vv.u[0] = 0x3f803f80u;
            vv.u[1] = 0x3f803f80u;
        } else {
            vv.u[0] = pkbf(acc[k][0], acc[k][1]);
            vv.u[1] = pkbf(acc[k][2], acc[k][3]);
        }
        size_t unit = ((size_t)(b * NG32 + g32) * 8 + (c >> 4)) * 64 + quadn * 16 + (c & 15);
        *(short4v*)&vfrag[unit * 8 + halfn] = vv.s;
    }
    __syncthreads();
    if (tid < 32) {
        float s = 0.f;
#pragma unroll
        for (int og2 = 0; og2 < 32; ++og2) s += msh[og2][tid];
        m2[(size_t)b * NN + n0 + tid] = s * 1.44269504088896340736f;
    }
}

// ---------------------------------------------------------------------------
// Flash attention (R12 skip structure) + V STAGING REMOVED:
// the adaptive skip makes PV fire on only ~2% of (wave,window) pairs, so
// staging V every chunk (16 DMA pieces + 32KB LDS + drain share) feeds MFMAs
// that almost never run. K-only staging (all 4 waves x 4 pieces); in the
// rare fire path V is loaded on demand global->reg (L2-resident, lane-exact
// vfrag layout -- address identity verified against the staged path).
// ---------------------------------------------------------------------------
__global__ __launch_bounds__(256, 2) void attn_kernel(const unsigned short* __restrict__ kfrag,
                                                      const unsigned short* __restrict__ vfrag,
                                                      const float* __restrict__ m2,
                                                      unsigned short* __restrict__ opart) {
    __shared__ __align__(16) unsigned short kbuf[2][16 * 512];   // 16 KB each (K only)
    // XCD x (= id%8) serves grps {2x,2x+1}: ~1MB L2-resident stream per XCD
    const int id = blockIdx.x;
    const int ghi = id & 7;
    const int r_ = id >> 3;
    const int mtile = r_ & 31;
    const int glo = r_ >> 5;          // 0..1
    const int grp = ghi * 2 + glo;    // 0..15
    const int b = grp & 3;
    const int split = grp >> 2;       // 0..3
    const int w = threadIdx.x >> 6;
    const int lane = threadIdx.x & 63;
    const int col = lane & 15;
    const int quad = lane >> 4;
    const int m0 = mtile * 128 + w * 32;
    const floatx4 fzero = {0.f, 0.f, 0.f, 0.f};
    const float L2E = 1.44269504088896340736f;

    // Q frags (B operand of swapped QK), position-indexed, register-resident
    short8 qf[2][4];
#pragma unroll
    for (int ms = 0; ms < 2; ++ms) {
        const int gq = (m0 >> 4) + ms;
#pragma unroll
        for (int t = 0; t < 4; ++t)
            qf[ms][t] = *(const short8*)&kfrag[((size_t)(b * NGRP + gq) * 4 + t) * 512 + lane * 8];
    }
    // stabilizer of the ACTUAL query at position col of subtile ms
    const int mq = 8 * (col >> 2) + (col & 3);
    float nmreg[2];
    nmreg[0] = -m2[(size_t)b * NN + m0 + mq];
    nmreg[1] = -m2[(size_t)b * NN + m0 + mq + 4];

    floatx4 oacc[2][8];
#pragma unroll
    for (int ms = 0; ms < 2; ++ms)
#pragma unroll
        for (int s8 = 0; s8 < 8; ++s8) oacc[ms][s8] = fzero;

    // per-wave V base (on-demand fire path): piece (ch,u2,s8) at
    // ((b*NG32 + split*(KSPLIT>>5) + ch*2 + u2)*8 + s8)*512 + lane*8
    const unsigned short* vbase =
        vfrag + ((size_t)(b * NG32 + split * (KSPLIT >> 5)) * 8) * 512 + lane * 8;

    // 16 x 1KB K pieces per chunk; ALL 4 waves stage 4 each
    auto stage = [&](int ch, int sel) {
        const int g16b = split * (KSPLIT >> 4) + ch * 4;
#pragma unroll
        for (int i = 0; i < 4; ++i) {
            int p = w * 4 + i;
            const unsigned short* src =
                kfrag + ((size_t)(b * NGRP + g16b + (p >> 2)) * 4 + (p & 3)) * 512 + lane * 8;
            gl16(src, &kbuf[sel][p * 512]);
        }
    };

    stage(0, 0);
#pragma unroll 2
    for (int ch = 0; ch < NCHUNK; ++ch) {
        const int sel = ch & 1;
        __syncthreads();                       // drains staging DMA + guards buffer reuse
        if (ch + 1 < NCHUNK) stage(ch + 1, sel ^ 1);
        // ---- S^T = K Q^T over 64 key-positions ----
        floatx4 st[2][4];
#pragma unroll
        for (int ms = 0; ms < 2; ++ms)
#pragma unroll
            for (int u = 0; u < 4; ++u) st[ms][u] = fzero;
#pragma unroll
        for (int t = 0; t < 4; ++t) {
#pragma unroll
            for (int u = 0; u < 4; ++u) {
                short8 kf = *(const short8*)&kbuf[sel][((u * 4 + t) * 64 + lane) * 8];
                st[0][u] = __builtin_amdgcn_mfma_f32_16x16x32_bf16(kf, qf[0][t], st[0][u], 0, 0, 0);
                st[1][u] = __builtin_amdgcn_mfma_f32_16x16x32_bf16(kf, qf[1][t], st[1][u], 0, 0, 0);
            }
        }
        // ---- adaptive skip test: max score-arg over this wave's tile ----
        float mx = -1e30f;
#pragma unroll
        for (int ms = 0; ms < 2; ++ms)
#pragma unroll
            for (int u = 0; u < 4; ++u)
#pragma unroll
                for (int r = 0; r < 4; ++r)
                    mx = fmaxf(mx, __builtin_fmaf(st[ms][u][r], L2E, nmreg[ms]));
        if (__ballot(mx > SKIP_THR) != 0ull) {
            // ---- softmax numerator -> K=32 PV A-frags (registers only) ----
            float ev[2][4][4];
#pragma unroll
            for (int ms = 0; ms < 2; ++ms)
#pragma unroll
                for (int u = 0; u < 4; ++u)
#pragma unroll
                    for (int r = 0; r < 4; ++r)
                        ev[ms][u][r] = exp2_raw(__builtin_fmaf(st[ms][u][r], L2E, nmreg[ms]));
            PK8 af[2][2];
#pragma unroll
            for (int ms = 0; ms < 2; ++ms)
#pragma unroll
                for (int u2 = 0; u2 < 2; ++u2) {
                    af[ms][u2].u[0] = pkbf(ev[ms][2 * u2][0], ev[ms][2 * u2][1]);
                    af[ms][u2].u[1] = pkbf(ev[ms][2 * u2][2], ev[ms][2 * u2][3]);
                    af[ms][u2].u[2] = pkbf(ev[ms][2 * u2 + 1][0], ev[ms][2 * u2 + 1][1]);
                    af[ms][u2].u[3] = pkbf(ev[ms][2 * u2 + 1][2], ev[ms][2 * u2 + 1][3]);
                }
            // ---- O += P V (on-demand V: global->reg, L2-resident) ----
#pragma unroll
            for (int u2 = 0; u2 < 2; ++u2) {
#pragma unroll
                for (int s8 = 0; s8 < 8; ++s8) {
                    short8 vf = *(const short8*)(vbase + (size_t)((ch * 2 + u2) * 8 + s8) * 512);
                    oacc[0][s8] = __builtin_amdgcn_mfma_f32_16x16x32_bf16(af[0][u2].s, vf, oacc[0][s8], 0, 0, 0);
                    oacc[1][s8] = __builtin_amdgcn_mfma_f32_16x16x32_bf16(af[1][u2].s, vf, oacc[1][s8], 0, 0, 0);
                }
            }
        }
    }
    // ---- epilogue: position -> actual query remap, bf16 partials ----
    unsigned short* ob = opart + (size_t)(split * BB + b) * NN * CP;
#pragma unroll
    for (int ms = 0; ms < 2; ++ms)
#pragma unroll
        for (int s8 = 0; s8 < 8; ++s8)
#pragma unroll
            for (int r = 0; r < 4; ++r)
                ob[(size_t)(m0 + 8 * quad + 4 * ms + r) * CP + s8 * 16 + col] = f2bf_fast(oacc[ms][s8][r]);
}

// ---------------------------------------------------------------------------
// Linear combine of 4 split partials (L from channel 124) + normalize +
// gamma*E + x; LDS transpose for contiguous [b][c][m] writes.
// ---------------------------------------------------------------------------
__global__ __launch_bounds__(256) void combine_kernel(const unsigned short* __restrict__ opart,
                                                      const float* __restrict__ x,
                                                      const float* __restrict__ gamma,
                                                      float* __restrict__ out) {
    __shared__ float es[32 * 133];
    __shared__ float Lsh[32];
    const int t = threadIdx.x;
    const int b = blockIdx.y;
    const int m0 = blockIdx.x * 32;
    if (t < 32) {
        float L = 0.f;
#pragma unroll
        for (int s = 0; s < NSPLIT; ++s)
            L += bf2f(opart[((size_t)(s * BB + b) * NN + m0 + t) * CP + 124]);
        Lsh[t] = gamma[0] / L;
    }
    const int tc = t & 31, tm = t >> 5;
    float acc[4][4];
#pragma unroll
    for (int i = 0; i < 4; ++i)
#pragma unroll
        for (int j = 0; j < 4; ++j) acc[i][j] = 0.f;
    for (int s = 0; s < NSPLIT; ++s) {
        const unsigned short* obp = opart + ((size_t)(s * BB + b) * NN + m0 + tm * 4) * CP + tc * 4;
#pragma unroll
        for (int i = 0; i < 4; ++i) {
            short4v v = *(const short4v*)(obp + (size_t)i * CP);
            acc[i][0] += bf2f((unsigned short)v[0]);
            acc[i][1] += bf2f((unsigned short)v[1]);
            acc[i][2] += bf2f((unsigned short)v[2]);
            acc[i][3] += bf2f((unsigned short)v[3]);
        }
    }
#pragma unroll
    for (int i = 0; i < 4; ++i)
#pragma unroll
        for (int j = 0; j < 4; ++j) es[(tm * 4 + i) * 133 + tc * 4 + j] = acc[i][j];
    __syncthreads();
    const int wave = t >> 6, lane = t & 63;
    const int half = lane >> 5, lm = lane & 31;
#pragma unroll
    for (int p = 0; p < 16; ++p) {
        int c = p * 8 + wave * 2 + half;
        if (c < CC) {
            size_t base = ((size_t)b * CC + c) * NN + m0 + lm;
            out[base] = es[lm * 133 + c] * Lsh[lm] + x[base];
        }
    }
}

extern "C" void kernel_launch(void* const* d_in, const int* in_sizes, int n_in,
                              void* d_out, int out_size, void* d_ws, size_t ws_size,
                              hipStream_t stream) {
    const float* x = (const float*)d_in[0];
    const float* Wb = (const float*)d_in[1];
    const float* gamma = (const float*)d_in[2];
    float* out = (float*)d_out;

    const size_t kfrag_b = (size_t)BB * NGRP * 4 * 64 * 8 * sizeof(unsigned short);   // 4 MB
    const size_t vfrag_b = (size_t)BB * NG32 * 8 * 64 * 8 * sizeof(unsigned short);   // 4 MB
    const size_t m2_b = (size_t)BB * NN * sizeof(float);                               // 64 KB
    const size_t opart_b = (size_t)NSPLIT * BB * NN * CP * sizeof(unsigned short);     // 16 MB
    const size_t wbt_b = (size_t)CC * CP * sizeof(unsigned short);                     // 32 KB
    if (ws_size < kfrag_b + vfrag_b + m2_b + opart_b + wbt_b) return;

    char* w = (char*)d_ws;
    unsigned short* kfrag = (unsigned short*)w;
    unsigned short* vfrag = (unsigned short*)(w + kfrag_b);
    float* m2 = (float*)(w + kfrag_b + vfrag_b);
    unsigned short* opart = (unsigned short*)(w + kfrag_b + vfrag_b + m2_b);
    unsigned short* wbt = (unsigned short*)(w + kfrag_b + vfrag_b + m2_b + opart_b);

    wtrans_kernel<<<dim3(4), 256, 0, stream>>>(Wb, wbt);
    bf_proj_kernel<<<dim3(NN / 32, BB), 256, 0, stream>>>(x, wbt, kfrag, vfrag, m2);
    attn_kernel<<<dim3(512), 256, 0, stream>>>(kfrag, vfrag, m2, opart);
    combine_kernel<<<dim3(NN / 32, BB), 256, 0, stream>>>(opart, x, gamma, out);
}

// Round 14
// 115.873 us; speedup vs baseline: 1.0275x; 1.0275x over previous
//
#include <hip/hip_runtime.h>

typedef short short8 __attribute__((ext_vector_type(8)));
typedef short short4v __attribute__((ext_vector_type(4)));
typedef float floatx4 __attribute__((ext_vector_type(4)));

#define BB 4
#define CC 124
#define CP 128
#define NN 4096
#define NGRP 256               // 16-position groups per batch (kfrag)
#define NG32 128               // 32-key groups per batch (vfrag)
#define NSPLIT 4
#define KSPLIT (NN / NSPLIT)   // 1024 keys per split
#define TN 64                  // keys per chunk
#define NCHUNK (KSPLIT / TN)   // 16
// retained-set softmax cutoff (log2 units): contributions < 2^-24 dropped.
// off-diag args here are ~-179 +- 16, diag = 0 -> skip fires on ~98% of
// (wave,window) pairs; dropped mass <= 4096*2^-24*|V|*gamma/L ~ 1e-4.
// [R12 measured: attn 40.6 -> 31.6us, total 116.07us, absmax 0.03125]
// [R13 measured: REMOVING V staging regressed +3us -> V staging is fully
//  overlapped (not on critical path); keep it. Final structure.]
#define SKIP_THR -24.0f

static __device__ __forceinline__ unsigned short f2bf_fast(float f) {
    return (unsigned short)((__float_as_uint(f) + 0x8000u) >> 16);
}
static __device__ __forceinline__ float bf2f(unsigned short u) {
    return __uint_as_float(((unsigned int)u) << 16);
}
// pack bf16(a) low16 | bf16(b) high16: 2 adds + 1 v_perm
static __device__ __forceinline__ unsigned int pkbf(float a, float b) {
    unsigned int ua = __float_as_uint(a) + 0x8000u;
    unsigned int ub = __float_as_uint(b) + 0x8000u;
    return __builtin_amdgcn_perm(ub, ua, 0x07060302u);
}
union PK2 { short4v s; unsigned int u[2]; };
union PK8 { short8 s; unsigned int u[4]; };

// Raw hardware exp2: libm exp2f (no fast-math) emits a ~7-inst guarded
// sequence for args < -126; our stabilized scores hit that range constantly
// and the flush-to-zero result is numerically irrelevant (L >= ~1).
#if defined(__has_builtin) && __has_builtin(__builtin_amdgcn_exp2f)
static __device__ __forceinline__ float exp2_raw(float x) {
    return __builtin_amdgcn_exp2f(x);
}
#else
static __device__ __forceinline__ float exp2_raw(float x) {
    float r;
    // s_nop 0 = 1 wait state for the TRANS->VALU consumer hazard
    asm("v_exp_f32 %0, %1\n\ts_nop 0" : "=v"(r) : "v"(x));
    return r;
}
#endif

// async global->LDS: 16B/lane, lds dest = wave-uniform base + lane*16
static __device__ __forceinline__ void gl16(const unsigned short* g, unsigned short* l) {
    __builtin_amdgcn_global_load_lds(
        (const __attribute__((address_space(1))) unsigned int*)g,
        (__attribute__((address_space(3))) unsigned int*)l, 16, 0, 0);
}

// ---------------------------------------------------------------------------
// One-time Wb transpose -> wbt[c][o] bf16 (o padded to 128 with zeros).
// Coalesced Wb reads, LDS transpose (stride-125 conflict-free), coalesced writes.
// ---------------------------------------------------------------------------
__global__ __launch_bounds__(256) void wtrans_kernel(const float* __restrict__ Wb,
                                                     unsigned short* __restrict__ wbt) {
    __shared__ float ws[32][125];
    const int blk = blockIdx.x;      // o-range blk*32 .. +31
    const int tid = threadIdx.x;
    for (int i = tid; i < 32 * CC; i += 256) {
        int ol = i / CC, c = i - ol * CC;
        int o = blk * 32 + ol;
        ws[ol][c] = (o < CC) ? Wb[o * CC + c] : 0.f;
    }
    __syncthreads();
    for (int i = tid; i < CC * 32; i += 256) {
        int c = i >> 5, ol = i & 31;
        wbt[c * CP + blk * 32 + ol] = f2bf_fast(ws[ol][c]);
    }
}

// ---------------------------------------------------------------------------
// Projection Bf = Wb x -> bf16 MFMA fragments, with the PV-enabling KEY
// PERMUTATION baked in:  position p within each 32-block = 16*((n>>2)&1) +
// 4*((n>>3)&3) + (n&3).  kfrag is position-indexed (QK A and Q B operands);
// vfrag is K=32 B-frag layout in ACTUAL key order:
//   vfrag[b][g32][s8][lane]*8 : 16B = V[keys 8*quad..+8][c = s8*16+col]
// V channel 124 = 1.0 -> PV computes l in O[m][124] for free.
// m2[b][n] = log2(e)*||Bf[:,n]||^2 (fixed stabilizer; diagonal dominates).
// Wb read from global wbt (L1-resident 32KB broadcast) -- no W in LDS.
// ---------------------------------------------------------------------------
__global__ __launch_bounds__(256, 4) void bf_proj_kernel(const float* __restrict__ x,
                                                         const unsigned short* __restrict__ wbt,
                                                         unsigned short* __restrict__ kfrag,
                                                         unsigned short* __restrict__ vfrag,
                                                         float* __restrict__ m2) {
    __shared__ __align__(16) float xs[CC][36];
    __shared__ float msh[32][33];
    const int tid = threadIdx.x;
    const int b = blockIdx.y;
    const int n0 = blockIdx.x * 32;
    const float* xb = x + (size_t)b * CC * NN + n0;
    for (int i = tid; i < CC * 8; i += 256) {
        int c = i >> 3, nq = i & 7;
        *(floatx4*)&xs[c][nq * 4] = *(const floatx4*)(xb + (size_t)c * NN + nq * 4);
    }
    __syncthreads();
    const int og = tid >> 3;        // 0..31 -> o0 = og*4
    const int nidx = tid & 7;       // key n_loc = nidx*4 + j
    const int o0 = og * 4;
    float acc[4][4];
#pragma unroll
    for (int k = 0; k < 4; ++k)
#pragma unroll
        for (int j = 0; j < 4; ++j) acc[k][j] = 0.f;
    for (int c = 0; c < CC; ++c) {
        floatx4 xv = *(const floatx4*)&xs[c][nidx * 4];
        short4v wv = *(const short4v*)&wbt[c * CP + o0];
#pragma unroll
        for (int k = 0; k < 4; ++k) {
            float wf = bf2f((unsigned short)wv[k]);
            acc[k][0] += wf * xv[0];
            acc[k][1] += wf * xv[1];
            acc[k][2] += wf * xv[2];
            acc[k][3] += wf * xv[3];
        }
    }
    // stats (per-n partial over this thread's 4 channels)
    float sq[4] = {0.f, 0.f, 0.f, 0.f};
#pragma unroll
    for (int k = 0; k < 4; ++k)
#pragma unroll
        for (int j = 0; j < 4; ++j) sq[j] += acc[k][j] * acc[k][j];
#pragma unroll
    for (int j = 0; j < 4; ++j) msh[og][nidx * 4 + j] = sq[j];
    // ---- kfrag (position-permuted) ----
    const int g16 = (n0 >> 4) + (nidx & 1);      // (n0>>5)*2 + (nidx&1)
    const int tK = o0 >> 5;
    const int qK = (o0 >> 3) & 3;
    const int halfo = o0 & 7;                    // 0 or 4 shorts
#pragma unroll
    for (int j = 0; j < 4; ++j) {
        PK2 kv;
        kv.u[0] = pkbf(acc[0][j], acc[1][j]);
        kv.u[1] = pkbf(acc[2][j], acc[3][j]);
        int row16 = 4 * (nidx >> 1) + j;         // p & 15
        size_t unit = ((size_t)(b * NGRP + g16) * 4 + tK) * 64 + qK * 16 + row16;
        *(short4v*)&kfrag[unit * 8 + halfo] = kv.s;
    }
    // ---- vfrag (K=32 B-frags, natural key order) ----
    const int g32 = n0 >> 5;
    const int quadn = nidx >> 1;                 // (n_loc)>>3
    const int halfn = (nidx & 1) * 4;            // element offset j_in_8 base
#pragma unroll
    for (int k = 0; k < 4; ++k) {
        int c = o0 + k;
        PK2 vv;
        if (c == 124) {
            vv.u[0] = 0x3f803f80u;
            vv.u[1] = 0x3f803f80u;
        } else {
            vv.u[0] = pkbf(acc[k][0], acc[k][1]);
            vv.u[1] = pkbf(acc[k][2], acc[k][3]);
        }
        size_t unit = ((size_t)(b * NG32 + g32) * 8 + (c >> 4)) * 64 + quadn * 16 + (c & 15);
        *(short4v*)&vfrag[unit * 8 + halfn] = vv.s;
    }
    __syncthreads();
    if (tid < 32) {
        float s = 0.f;
#pragma unroll
        for (int og2 = 0; og2 < 32; ++og2) s += msh[og2][tid];
        m2[(size_t)b * NN + n0 + tid] = s * 1.44269504088896340736f;
    }
}

// ---------------------------------------------------------------------------
// Flash attention (R1 structure) + ADAPTIVE CHUNK SKIP:
// after QK, if every lane's max score-arg < SKIP_THR (retained-set softmax
// cutoff 2^-24), the wave skips exp+pack+PV for the window -- on this op's
// diagonal-dominant scores that is ~98% of (wave,window) pairs, halving MFMA
// work and dropping most VALU. QK always runs (dominance is statistical).
// Wave-uniform branch via ballot; skipped waves idle at the barrier, freeing
// the SIMD for the co-resident block. V STAGING KEPT (R13: removal = +3us).
// ---------------------------------------------------------------------------
__global__ __launch_bounds__(256, 2) void attn_kernel(const unsigned short* __restrict__ kfrag,
                                                      const unsigned short* __restrict__ vfrag,
                                                      const float* __restrict__ m2,
                                                      unsigned short* __restrict__ opart) {
    __shared__ __align__(16) unsigned short kbuf[2][16 * 512];   // 16 KB each
    __shared__ __align__(16) unsigned short vbuf[2][16 * 512];   // 16 KB each
    // XCD x (= id%8) serves grps {2x,2x+1}: ~1MB L2-resident stream per XCD
    const int id = blockIdx.x;
    const int ghi = id & 7;
    const int r_ = id >> 3;
    const int mtile = r_ & 31;
    const int glo = r_ >> 5;          // 0..1
    const int grp = ghi * 2 + glo;    // 0..15
    const int b = grp & 3;
    const int split = grp >> 2;       // 0..3
    const int w = threadIdx.x >> 6;
    const int lane = threadIdx.x & 63;
    const int col = lane & 15;
    const int quad = lane >> 4;
    const int m0 = mtile * 128 + w * 32;
    const floatx4 fzero = {0.f, 0.f, 0.f, 0.f};
    const float L2E = 1.44269504088896340736f;

    // Q frags (B operand of swapped QK), position-indexed, register-resident
    short8 qf[2][4];
#pragma unroll
    for (int ms = 0; ms < 2; ++ms) {
        const int gq = (m0 >> 4) + ms;
#pragma unroll
        for (int t = 0; t < 4; ++t)
            qf[ms][t] = *(const short8*)&kfrag[((size_t)(b * NGRP + gq) * 4 + t) * 512 + lane * 8];
    }
    // stabilizer of the ACTUAL query at position col of subtile ms
    const int mq = 8 * (col >> 2) + (col & 3);
    float nmreg[2];
    nmreg[0] = -m2[(size_t)b * NN + m0 + mq];
    nmreg[1] = -m2[(size_t)b * NN + m0 + mq + 4];

    floatx4 oacc[2][8];
#pragma unroll
    for (int ms = 0; ms < 2; ++ms)
#pragma unroll
        for (int s8 = 0; s8 < 8; ++s8) oacc[ms][s8] = fzero;

    // 32 x 1KB pieces per chunk (16 K + 16 V); wave w stages 8
    auto stage = [&](int ch, int sel) {
        if (w < 2) {
            const int g16b = split * (KSPLIT >> 4) + ch * 4;
#pragma unroll
            for (int i = 0; i < 8; ++i) {
                int p = w * 8 + i;
                const unsigned short* src =
                    kfrag + ((size_t)(b * NGRP + g16b + (p >> 2)) * 4 + (p & 3)) * 512 + lane * 8;
                gl16(src, &kbuf[sel][p * 512]);
            }
        } else {
            const int g32b = split * (KSPLIT >> 5) + ch * 2;
#pragma unroll
            for (int i = 0; i < 8; ++i) {
                int q = (w - 2) * 8 + i;
                const unsigned short* src =
                    vfrag + ((size_t)(b * NG32 + g32b + (q >> 3)) * 8 + (q & 7)) * 512 + lane * 8;
                gl16(src, &vbuf[sel][q * 512]);
            }
        }
    };

    stage(0, 0);
#pragma unroll 2
    for (int ch = 0; ch < NCHUNK; ++ch) {
        const int sel = ch & 1;
        __syncthreads();                       // drains staging DMA + guards buffer reuse
        if (ch + 1 < NCHUNK) stage(ch + 1, sel ^ 1);
        // ---- S^T = K Q^T over 64 key-positions ----
        floatx4 st[2][4];
#pragma unroll
        for (int ms = 0; ms < 2; ++ms)
#pragma unroll
            for (int u = 0; u < 4; ++u) st[ms][u] = fzero;
#pragma unroll
        for (int t = 0; t < 4; ++t) {
#pragma unroll
            for (int u = 0; u < 4; ++u) {
                short8 kf = *(const short8*)&kbuf[sel][((u * 4 + t) * 64 + lane) * 8];
                st[0][u] = __builtin_amdgcn_mfma_f32_16x16x32_bf16(kf, qf[0][t], st[0][u], 0, 0, 0);
                st[1][u] = __builtin_amdgcn_mfma_f32_16x16x32_bf16(kf, qf[1][t], st[1][u], 0, 0, 0);
            }
        }
        // ---- adaptive skip test: max score-arg over this wave's tile ----
        float mx = -1e30f;
#pragma unroll
        for (int ms = 0; ms < 2; ++ms)
#pragma unroll
            for (int u = 0; u < 4; ++u)
#pragma unroll
                for (int r = 0; r < 4; ++r)
                    mx = fmaxf(mx, __builtin_fmaf(st[ms][u][r], L2E, nmreg[ms]));
        if (__ballot(mx > SKIP_THR) != 0ull) {
            // ---- softmax numerator -> K=32 PV A-frags (registers only) ----
            float ev[2][4][4];
#pragma unroll
            for (int ms = 0; ms < 2; ++ms)
#pragma unroll
                for (int u = 0; u < 4; ++u)
#pragma unroll
                    for (int r = 0; r < 4; ++r)
                        ev[ms][u][r] = exp2_raw(__builtin_fmaf(st[ms][u][r], L2E, nmreg[ms]));
            PK8 af[2][2];
#pragma unroll
            for (int ms = 0; ms < 2; ++ms)
#pragma unroll
                for (int u2 = 0; u2 < 2; ++u2) {
                    af[ms][u2].u[0] = pkbf(ev[ms][2 * u2][0], ev[ms][2 * u2][1]);
                    af[ms][u2].u[1] = pkbf(ev[ms][2 * u2][2], ev[ms][2 * u2][3]);
                    af[ms][u2].u[2] = pkbf(ev[ms][2 * u2 + 1][0], ev[ms][2 * u2 + 1][1]);
                    af[ms][u2].u[3] = pkbf(ev[ms][2 * u2 + 1][2], ev[ms][2 * u2 + 1][3]);
                }
            // ---- O += P V (full-rate K=32 MFMAs) ----
#pragma unroll
            for (int u2 = 0; u2 < 2; ++u2) {
#pragma unroll
                for (int s8 = 0; s8 < 8; ++s8) {
                    short8 vf = *(const short8*)&vbuf[sel][((u2 * 8 + s8) * 64 + lane) * 8];
                    oacc[0][s8] = __builtin_amdgcn_mfma_f32_16x16x32_bf16(af[0][u2].s, vf, oacc[0][s8], 0, 0, 0);
                    oacc[1][s8] = __builtin_amdgcn_mfma_f32_16x16x32_bf16(af[1][u2].s, vf, oacc[1][s8], 0, 0, 0);
                }
            }
        }
    }
    // ---- epilogue: position -> actual query remap, bf16 partials ----
    unsigned short* ob = opart + (size_t)(split * BB + b) * NN * CP;
#pragma unroll
    for (int ms = 0; ms < 2; ++ms)
#pragma unroll
        for (int s8 = 0; s8 < 8; ++s8)
#pragma unroll
            for (int r = 0; r < 4; ++r)
                ob[(size_t)(m0 + 8 * quad + 4 * ms + r) * CP + s8 * 16 + col] = f2bf_fast(oacc[ms][s8][r]);
}

// ---------------------------------------------------------------------------
// Linear combine of 4 split partials (L from channel 124) + normalize +
// gamma*E + x; LDS transpose for contiguous [b][c][m] writes.
// ---------------------------------------------------------------------------
__global__ __launch_bounds__(256) void combine_kernel(const unsigned short* __restrict__ opart,
                                                      const float* __restrict__ x,
                                                      const float* __restrict__ gamma,
                                                      float* __restrict__ out) {
    __shared__ float es[32 * 133];
    __shared__ float Lsh[32];
    const int t = threadIdx.x;
    const int b = blockIdx.y;
    const int m0 = blockIdx.x * 32;
    if (t < 32) {
        float L = 0.f;
#pragma unroll
        for (int s = 0; s < NSPLIT; ++s)
            L += bf2f(opart[((size_t)(s * BB + b) * NN + m0 + t) * CP + 124]);
        Lsh[t] = gamma[0] / L;
    }
    const int tc = t & 31, tm = t >> 5;
    float acc[4][4];
#pragma unroll
    for (int i = 0; i < 4; ++i)
#pragma unroll
        for (int j = 0; j < 4; ++j) acc[i][j] = 0.f;
    for (int s = 0; s < NSPLIT; ++s) {
        const unsigned short* obp = opart + ((size_t)(s * BB + b) * NN + m0 + tm * 4) * CP + tc * 4;
#pragma unroll
        for (int i = 0; i < 4; ++i) {
            short4v v = *(const short4v*)(obp + (size_t)i * CP);
            acc[i][0] += bf2f((unsigned short)v[0]);
            acc[i][1] += bf2f((unsigned short)v[1]);
            acc[i][2] += bf2f((unsigned short)v[2]);
            acc[i][3] += bf2f((unsigned short)v[3]);
        }
    }
#pragma unroll
    for (int i = 0; i < 4; ++i)
#pragma unroll
        for (int j = 0; j < 4; ++j) es[(tm * 4 + i) * 133 + tc * 4 + j] = acc[i][j];
    __syncthreads();
    const int wave = t >> 6, lane = t & 63;
    const int half = lane >> 5, lm = lane & 31;
#pragma unroll
    for (int p = 0; p < 16; ++p) {
        int c = p * 8 + wave * 2 + half;
        if (c < CC) {
            size_t base = ((size_t)b * CC + c) * NN + m0 + lm;
            out[base] = es[lm * 133 + c] * Lsh[lm] + x[base];
        }
    }
}

extern "C" void kernel_launch(void* const* d_in, const int* in_sizes, int n_in,
                              void* d_out, int out_size, void* d_ws, size_t ws_size,
                              hipStream_t stream) {
    const float* x = (const float*)d_in[0];
    const float* Wb = (const float*)d_in[1];
    const float* gamma = (const float*)d_in[2];
    float* out = (float*)d_out;

    const size_t kfrag_b = (size_t)BB * NGRP * 4 * 64 * 8 * sizeof(unsigned short);   // 4 MB
    const size_t vfrag_b = (size_t)BB * NG32 * 8 * 64 * 8 * sizeof(unsigned short);   // 4 MB
    const size_t m2_b = (size_t)BB * NN * sizeof(float);                               // 64 KB
    const size_t opart_b = (size_t)NSPLIT * BB * NN * CP * sizeof(unsigned short);     // 16 MB
    const size_t wbt_b = (size_t)CC * CP * sizeof(unsigned short);                     // 32 KB
    if (ws_size < kfrag_b + vfrag_b + m2_b + opart_b + wbt_b) return;

    char* w = (char*)d_ws;
    unsigned short* kfrag = (unsigned short*)w;
    unsigned short* vfrag = (unsigned short*)(w + kfrag_b);
    float* m2 = (float*)(w + kfrag_b + vfrag_b);
    unsigned short* opart = (unsigned short*)(w + kfrag_b + vfrag_b + m2_b);
    unsigned short* wbt = (unsigned short*)(w + kfrag_b + vfrag_b + m2_b + opart_b);

    wtrans_kernel<<<dim3(4), 256, 0, stream>>>(Wb, wbt);
    bf_proj_kernel<<<dim3(NN / 32, BB), 256, 0, stream>>>(x, wbt, kfrag, vfrag, m2);
    attn_kernel<<<dim3(512), 256, 0, stream>>>(kfrag, vfrag, m2, opart);
    combine_kernel<<<dim3(NN / 32, BB), 256, 0, stream>>>(opart, x, gamma, out);
}